// Round 13
// baseline (218.160 us; speedup 1.0000x reference)
//
#include <hip/hip_runtime.h>

typedef unsigned short u16;
typedef unsigned int u32;
typedef u16 u16x4 __attribute__((ext_vector_type(4)));
typedef u16 u16x8 __attribute__((ext_vector_type(8)));
typedef u32 u32x2 __attribute__((ext_vector_type(2)));
typedef u32 u32x4 __attribute__((ext_vector_type(4)));
typedef __bf16 bf16x2 __attribute__((ext_vector_type(2)));
typedef __bf16 bf16x8 __attribute__((ext_vector_type(8)));
typedef float f32x4 __attribute__((ext_vector_type(4)));

__device__ __forceinline__ u16 f2bf(float f) {
  return __builtin_bit_cast(u16, (__bf16)f);
}

__device__ __forceinline__ u32 packbf2(float lo, float hi) {
  bf16x2 t;
  t[0] = (__bf16)lo;
  t[1] = (__bf16)hi;
  return __builtin_bit_cast(u32, t);
}

__device__ __forceinline__ f32x4 mfma16(bf16x8 a, bf16x8 b, f32x4 c) {
  return __builtin_amdgcn_mfma_f32_16x16x32_bf16(a, b, c, 0, 0, 0);
}

#define GLOAD_LDS16(gsrc, ldst)                                              \
  __builtin_amdgcn_global_load_lds(                                          \
      (const __attribute__((address_space(1))) void*)(gsrc),                 \
      (__attribute__((address_space(3))) void*)(ldst), 16, 0, 0)

// ---------------- fp32 -> bf16 convert (x) ----------------
__global__ __launch_bounds__(256) void cvt_x(const float* __restrict__ in,
                                             u16* __restrict__ out, int n) {
  int i = (blockIdx.x * 256 + threadIdx.x) * 8;
  if (i >= n) return;
  u16x8 o;
#pragma unroll
  for (int j = 0; j < 8; j++) o[j] = f2bf(in[i + j]);
  *(u16x8*)&out[i] = o;
}

// ------------- transpose + convert: in [R][C] f32 -> out [C][R] bf16 -------------
__global__ __launch_bounds__(256) void transpose_cvt(const float* __restrict__ in,
                                                     u16* __restrict__ out,
                                                     int R, int C) {
  __shared__ float tile[32][33];
  int gx = blockIdx.x * 32, gy = blockIdx.y * 32;
  int tx = threadIdx.x, ty = threadIdx.y;
#pragma unroll
  for (int i = 0; i < 4; i++)
    tile[ty + i * 8][tx] = in[(size_t)(gy + ty + i * 8) * C + gx + tx];
  __syncthreads();
#pragma unroll
  for (int i = 0; i < 4; i++) {
    int c = ty + i * 8;
    out[(size_t)(gx + c) * R + gy + tx] = f2bf(tile[tx][c]);
  }
}

// ------------- 256x256 4-phase GEMM (QKV): C = A[M,K] * Bt[N,K]^T ---------------
// 512 thr = 8 waves (2M x 4N), wave tile 128x64. BK=64 as two k-halves.
// Pieces A0/A1/B0/B1 = [256][32] u16 (16 KB) x 2 bufs = 128 KB dynamic LDS.
// Swizzle (R9-validated, 0 conflicts): phys 16B-chunk = logical ^ ((row>>1)&3);
// linear gload dst, pre-swizzled global source (rule 21).
// Phase = {ds_read frags | stage batch (ph0/ph2) | barrier | lgkmcnt(0)+schedbar |
// setprio 16 MFMA | [vmcnt(4) ph1/ph3, BEFORE barrier] | barrier}. vmcnt never 0
// mid-loop; stage-to-use distance = 4 phases (T3+T4).
__global__ __launch_bounds__(512, 1) void gemm256(
    const u16* __restrict__ A, const u16* __restrict__ Bt,
    const float* __restrict__ bias, u16* __restrict__ qb, u16* __restrict__ kb,
    u16* __restrict__ vb, int N, int K, int NBN) {
  extern __shared__ u16 lds[];  // 65536 u16 = 128 KB
  const int tid = threadIdx.x;
  const int wid = tid >> 6;
  const int lane = tid & 63;
  const int wr = wid >> 2, wc = wid & 3;
  const int l15 = lane & 15, l4 = lane >> 4;

  // XCD grouping (grid % 8 == 0): contiguous id2 range per XCD, bm-major
  const int nb = gridDim.x;
  const int id2 = (blockIdx.x & 7) * (nb >> 3) + (blockIdx.x >> 3);
  const int bm = (id2 / NBN) * 256;
  const int bn = (id2 % NBN) * 256;

  const u16* Ab = A + (size_t)bm * K;
  const u16* Bb = Bt + (size_t)bn * K;

  // piece p: 0=A-klo 1=A-khi 2=B-klo 3=B-khi; each [256][32] u16, 2 buffers
#define PIECE(p, b) (lds + (p) * 16384 + (b) * 8192)

  // stage one piece (2 calls x 512 thr x 16B): rows c*128 + tid/4, chunk tid&3
  auto STAGEP = [&](u16* dst, const u16* srcb, int kofs) {
#pragma unroll
    for (int c = 0; c < 2; c++) {
      const int row = c * 128 + (tid >> 2);
      const int sch = (tid & 3) ^ ((row >> 1) & 3);
      GLOAD_LDS16(srcb + (size_t)row * K + kofs + sch * 8,
                  dst + c * 4096 + wid * 512);
    }
  };
  auto RDA = [&](const u16* arr, int mi) -> bf16x8 {
    const int row = wr * 128 + mi * 16 + l15;
    return *(const bf16x8*)&arr[row * 32 + ((l4 ^ ((row >> 1) & 3)) * 8)];
  };
  auto RDB = [&](const u16* arr, int ni) -> bf16x8 {
    const int row = wc * 64 + ni * 16 + l15;
    return *(const bf16x8*)&arr[row * 32 + ((l4 ^ ((row >> 1) & 3)) * 8)];
  };

  f32x4 acc[8][4] = {};
  bf16x8 af[8], bfr[2];

#define PH_MFMA(n0, n1)                                                      \
  do {                                                                       \
    asm volatile("s_waitcnt lgkmcnt(0)" ::: "memory");                       \
    __builtin_amdgcn_sched_barrier(0);                                       \
    __builtin_amdgcn_s_setprio(1);                                           \
    _Pragma("unroll") for (int mi = 0; mi < 8; mi++) {                       \
      acc[mi][n0] = mfma16(af[mi], bfr[0], acc[mi][n0]);                     \
      acc[mi][n1] = mfma16(af[mi], bfr[1], acc[mi][n1]);                     \
    }                                                                        \
    __builtin_amdgcn_s_setprio(0);                                           \
  } while (0)

  // prologue: stage tile 0 (A0,B0 first, then A1,B1)
  STAGEP(PIECE(0, 0), Ab, 0);
  STAGEP(PIECE(2, 0), Bb, 0);
  STAGEP(PIECE(1, 0), Ab, 32);
  STAGEP(PIECE(3, 0), Bb, 32);
  asm volatile("s_waitcnt vmcnt(4)" ::: "memory");  // A0,B0 landed (all waves)
  __builtin_amdgcn_s_barrier();

  const int NT = K >> 6;
  for (int t = 0; t < NT; ++t) {
    const int buf = t & 1, nbuf = buf ^ 1;
    const int kn = (t + 1) << 6;
    const bool pre = (t + 1 < NT);

    // ---- ph0: kg=0, ni 0-1; issue A0,B0 of tile t+1 ----
#pragma unroll
    for (int mi = 0; mi < 8; mi++) af[mi] = RDA(PIECE(0, buf), mi);
    bfr[0] = RDB(PIECE(2, buf), 0);
    bfr[1] = RDB(PIECE(2, buf), 1);
    if (pre) {
      STAGEP(PIECE(0, nbuf), Ab, kn);
      STAGEP(PIECE(2, nbuf), Bb, kn);
    }
    __builtin_amdgcn_s_barrier();
    PH_MFMA(0, 1);
    __builtin_amdgcn_s_barrier();

    // ---- ph1: kg=0, ni 2-3 (af reused) ----
    bfr[0] = RDB(PIECE(2, buf), 2);
    bfr[1] = RDB(PIECE(2, buf), 3);
    __builtin_amdgcn_s_barrier();
    PH_MFMA(2, 3);
    // A1,B1 of tile t confirmed (newest 4 in flight = A0,B0 of t+1)
    if (pre)
      asm volatile("s_waitcnt vmcnt(4)" ::: "memory");
    else
      asm volatile("s_waitcnt vmcnt(0)" ::: "memory");
    __builtin_amdgcn_s_barrier();

    // ---- ph2: kg=1, ni 0-1; issue A1,B1 of tile t+1 ----
#pragma unroll
    for (int mi = 0; mi < 8; mi++) af[mi] = RDA(PIECE(1, buf), mi);
    bfr[0] = RDB(PIECE(3, buf), 0);
    bfr[1] = RDB(PIECE(3, buf), 1);
    if (pre) {
      STAGEP(PIECE(1, nbuf), Ab, kn + 32);
      STAGEP(PIECE(3, nbuf), Bb, kn + 32);
    }
    __builtin_amdgcn_s_barrier();
    PH_MFMA(0, 1);
    __builtin_amdgcn_s_barrier();

    // ---- ph3: kg=1, ni 2-3 ----
    bfr[0] = RDB(PIECE(3, buf), 2);
    bfr[1] = RDB(PIECE(3, buf), 3);
    __builtin_amdgcn_s_barrier();
    PH_MFMA(2, 3);
    // A0,B0 of tile t+1 confirmed (newest 4 = A1,B1 of t+1)
    if (pre)
      asm volatile("s_waitcnt vmcnt(4)" ::: "memory");
    else
      asm volatile("s_waitcnt vmcnt(0)" ::: "memory");
    __builtin_amdgcn_s_barrier();
  }
#undef PH_MFMA

  // ---- QKV scatter epilogue (R9-validated) ----
#pragma unroll
  for (int mi = 0; mi < 8; mi++) {
#pragma unroll
    for (int ni = 0; ni < 4; ni++) {
      const int col = bn + wc * 64 + ni * 16 + l15;
      const float bv = bias[col];
      const int row0 = bm + wr * 128 + mi * 16 + l4 * 4;
      const int which = col >> 10;
      const int hc = col & 1023;
      const int h = hc >> 6, d = hc & 63;
#pragma unroll
      for (int r = 0; r < 4; r++) {
        const int row = row0 + r;
        const int b = row >> 11, tt = row & 2047;
        const float v = acc[mi][ni][r] + bv;
        if (which == 0)
          // 0.125 (1/sqrt(64)) * log2(e): softmax done in exp2 domain
          qb[((size_t)(b * 16 + h) * 2048 + tt) * 64 + d] = f2bf(v * 0.18033688f);
        else if (which == 1)
          kb[((size_t)(b * 16 + h) * 2048 + tt) * 64 + d] = f2bf(v);
        else {
          // k-permute within each 64-block so attn's PV B-frag is lane-local:
          // o=16n+4a+r  ->  o' = 32*(n>>1) + 8a + 4*(n&1) + r
          const int o = tt & 63;
          const int op = (o & 3) | (((o >> 4) & 1) << 2) |
                         (((o >> 2) & 3) << 3) | ((o >> 5) << 5);
          const int tp = (tt & ~63) | op;
          vb[((size_t)(b * 16 + h) * 64 + d) * 2048 + tp] = f2bf(v);
        }
      }
    }
  }
#undef PIECE
}

// ---------------- 128x128 GEMM (out-proj, R7 structure): fp32 out + bias --------
template <int GX>
__global__ __launch_bounds__(256, 3) void gemm_proj(
    const u16* __restrict__ A, const u16* __restrict__ Bt,
    const float* __restrict__ bias, float* __restrict__ fout, int N, int K) {
  __shared__ u16 As[3][128 * 32];
  __shared__ u16 Bs[3][128 * 32];
  const int tid = threadIdx.x;
  const int wave = tid >> 6;
  const int lane = tid & 63;
  const int wr = wave >> 1, wc = wave & 1;
  const int l15 = lane & 15, l4 = lane >> 4;

  const int id = blockIdx.y * GX + blockIdx.x;
  const int xcd = id & 7;
  const int j = id >> 3;
  const int bm = (xcd * 8 + j / GX) * 128;
  const int bn = (j % GX) * 128;

  const int srow = wave * 16 + (lane >> 2);
  const int slch = lane & 3;
  const int ldst = wave * 512;

  const u16* Abase = A + (size_t)bm * K;
  const u16* Bbase = Bt + (size_t)bn * K;

  f32x4 acc[4][4] = {};

  auto STAGE = [&](int buf, int k0) {
#pragma unroll
    for (int c = 0; c < 2; c++) {
      const int row = c * 64 + srow;
      const int sch = slch ^ ((row >> 1) & 3);
      GLOAD_LDS16(Abase + (size_t)row * K + k0 + sch * 8,
                  &As[buf][c * 2048 + ldst]);
      GLOAD_LDS16(Bbase + (size_t)row * K + k0 + sch * 8,
                  &Bs[buf][c * 2048 + ldst]);
    }
  };

  const int NT = K >> 5;
  STAGE(0, 0);
  STAGE(1, 32);
  int cur = 0;
  for (int t = 0; t < NT; ++t) {
    if (t + 1 < NT) {
      asm volatile("s_waitcnt lgkmcnt(0)\n\ts_waitcnt vmcnt(4)" ::: "memory");
    } else {
      asm volatile("s_waitcnt lgkmcnt(0)\n\ts_waitcnt vmcnt(0)" ::: "memory");
    }
    __builtin_amdgcn_sched_barrier(0);
    asm volatile("s_barrier" ::: "memory");

    if (t + 2 < NT) {
      int stg = cur + 2;
      if (stg >= 3) stg -= 3;
      STAGE(stg, (t + 2) * 32);
    }

    const u16* as = As[cur];
    const u16* bs = Bs[cur];
    bf16x8 af[4], bfr[4];
#pragma unroll
    for (int mi = 0; mi < 4; mi++) {
      const int row = wr * 64 + mi * 16 + l15;
      af[mi] = *(const bf16x8*)&as[row * 32 + ((l4 ^ ((row >> 1) & 3)) * 8)];
    }
#pragma unroll
    for (int ni = 0; ni < 4; ni++) {
      const int row = wc * 64 + ni * 16 + l15;
      bfr[ni] = *(const bf16x8*)&bs[row * 32 + ((l4 ^ ((row >> 1) & 3)) * 8)];
    }
    __builtin_amdgcn_s_setprio(1);
#pragma unroll
    for (int mi = 0; mi < 4; mi++)
#pragma unroll
      for (int ni = 0; ni < 4; ni++)
        acc[mi][ni] = mfma16(af[mi], bfr[ni], acc[mi][ni]);
    __builtin_amdgcn_s_setprio(0);
    cur = (cur == 2) ? 0 : cur + 1;
  }

#pragma unroll
  for (int mi = 0; mi < 4; mi++) {
#pragma unroll
    for (int ni = 0; ni < 4; ni++) {
      const int col = bn + wc * 64 + ni * 16 + l15;
      const float bv = bias[col];
      const int row0 = bm + wr * 64 + mi * 16 + l4 * 4;
#pragma unroll
      for (int r = 0; r < 4; r++)
        fout[(size_t)(row0 + r) * N + col] = acc[mi][ni][r] + bv;
    }
  }
}

// ---------------- flash attention (swapped-operand, transposed O) ----------------
// Q,K: [64 bh][2048][64] bf16 (Q pre-scaled by 0.125*log2e)
// Vt: [64 bh][64][2048] bf16, k-axis PERMUTED within 64-blocks (see epilogue)
// O: [4 b][2048 t][1024] bf16. STATIC-MAX softmax (p = exp2(s-16), 1/l cancels).
__global__ __launch_bounds__(256, 4) void attn_kernel(const u16* __restrict__ Q,
                                                      const u16* __restrict__ Kg,
                                                      const u16* __restrict__ Vt,
                                                      u16* __restrict__ O) {
  __shared__ u16 Ks[2][64 * 64];
  __shared__ u16 Vs[2][64 * 64];
  const int tid = threadIdx.x;
  const int wave = tid >> 6;
  const int lane = tid & 63;
  const int l15 = lane & 15, l4 = lane >> 4;

  const int id = blockIdx.y * 16 + blockIdx.x;
  const int xcd = id & 7;
  const int j = id >> 3;
  const int bh = xcd * 8 + (j >> 4);
  const int qt = j & 15;

  const u16* qg = Q + ((size_t)bh * 2048 + qt * 128 + wave * 32) * 64;
  bf16x8 qf[2][2];
#pragma unroll
  for (int mi = 0; mi < 2; mi++)
#pragma unroll
    for (int kg2 = 0; kg2 < 2; kg2++)
      qf[mi][kg2] = *(const bf16x8*)&qg[(mi * 16 + l15) * 64 + kg2 * 32 + l4 * 8];

  float lsum[2] = {0.f, 0.f};
  f32x4 oacc[4][2] = {};

  const int srow = wave * 8 + (lane >> 3);
  const int slch = lane & 7;
  const int ldst = wave * 512;
  const u16* kbase = Kg + (size_t)bh * 2048 * 64;
  const u16* vbase = Vt + (size_t)bh * 64 * 2048;

  auto STAGE = [&](int buf, int kt) {
#pragma unroll
    for (int c = 0; c < 2; c++) {
      const int row = c * 32 + srow;
      const int sch = slch ^ (row & 7);
      GLOAD_LDS16(kbase + (size_t)(kt * 64 + row) * 64 + sch * 8,
                  &Ks[buf][c * 2048 + ldst]);
      GLOAD_LDS16(vbase + (size_t)row * 2048 + kt * 64 + sch * 8,
                  &Vs[buf][c * 2048 + ldst]);
    }
  };

  STAGE(0, 0);
  int cur = 0;
  for (int kt = 0; kt < 32; kt++) {
    __syncthreads();
    if (kt + 1 < 32) STAGE(cur ^ 1, kt + 1);
    const u16* ks = Ks[cur];
    const u16* vs = Vs[cur];

    f32x4 sacc[2][4] = {};
    __builtin_amdgcn_s_setprio(1);
#pragma unroll
    for (int kg2 = 0; kg2 < 2; kg2++) {
#pragma unroll
      for (int ni = 0; ni < 4; ni++) {
        const int row = ni * 16 + l15;
        bf16x8 kf =
            *(const bf16x8*)&ks[row * 64 + (((kg2 * 4 + l4) ^ (row & 7)) * 8)];
#pragma unroll
        for (int mi = 0; mi < 2; mi++)
          sacc[mi][ni] = mfma16(kf, qf[mi][kg2], sacc[mi][ni]);
      }
    }
    __builtin_amdgcn_s_setprio(0);

#pragma unroll
    for (int mi = 0; mi < 2; mi++) {
      float rs = 0.f;
#pragma unroll
      for (int ni = 0; ni < 4; ni++)
#pragma unroll
        for (int r = 0; r < 4; r++) {
          const float p = __builtin_amdgcn_exp2f(sacc[mi][ni][r] - 16.0f);
          sacc[mi][ni][r] = p;
          rs += p;
        }
      lsum[mi] += rs;
    }

#pragma unroll
    for (int kg2 = 0; kg2 < 2; kg2++) {
      bf16x8 pf[2];
#pragma unroll
      for (int mi = 0; mi < 2; mi++) {
        u32x4 praw;
        praw[0] = packbf2(sacc[mi][2 * kg2][0], sacc[mi][2 * kg2][1]);
        praw[1] = packbf2(sacc[mi][2 * kg2][2], sacc[mi][2 * kg2][3]);
        praw[2] = packbf2(sacc[mi][2 * kg2 + 1][0], sacc[mi][2 * kg2 + 1][1]);
        praw[3] = packbf2(sacc[mi][2 * kg2 + 1][2], sacc[mi][2 * kg2 + 1][3]);
        pf[mi] = __builtin_bit_cast(bf16x8, praw);
      }
      __builtin_amdgcn_s_setprio(1);
#pragma unroll
      for (int di = 0; di < 4; di++) {
        const int row = di * 16 + l15;
        bf16x8 vf =
            *(const bf16x8*)&vs[row * 64 + (((kg2 * 4 + l4) ^ (row & 7)) * 8)];
#pragma unroll
        for (int mi = 0; mi < 2; mi++)
          oacc[di][mi] = mfma16(vf, pf[mi], oacc[di][mi]);
      }
      __builtin_amdgcn_s_setprio(0);
    }
    cur ^= 1;
  }

  const int b = bh >> 4, h = bh & 15;
#pragma unroll
  for (int mi = 0; mi < 2; mi++) {
    float lr = lsum[mi];
    lr += __shfl_xor(lr, 16);
    lr += __shfl_xor(lr, 32);
    const float invl = 1.0f / lr;
    const int t = qt * 128 + wave * 32 + mi * 16 + l15;
#pragma unroll
    for (int di = 0; di < 4; di++) {
      u16x4 o;
#pragma unroll
      for (int r = 0; r < 4; r++) o[r] = f2bf(oacc[di][mi][r] * invl);
      *(u16x4*)&O[((size_t)b * 2048 + t) * 1024 + h * 64 + di * 16 + l4 * 4] = o;
    }
  }
}

extern "C" void kernel_launch(void* const* d_in, const int* in_sizes, int n_in,
                              void* d_out, int out_size, void* d_ws, size_t ws_size,
                              hipStream_t stream) {
  const float* x = (const float*)d_in[0];
  const float* Wqkv = (const float*)d_in[1];
  const float* bqkv = (const float*)d_in[2];
  const float* Wout = (const float*)d_in[3];
  const float* bout = (const float*)d_in[4];
  float* out = (float*)d_out;

  u16* ws = (u16*)d_ws;
  u16* xb = ws;                  // 8192*1024
  u16* wqT = xb + 8388608;       // 3072*1024
  u16* woT = wqT + 3145728;      // 1024*1024
  u16* qb = woT + 1048576;       // 64*2048*64
  u16* kb = qb + 8388608;
  u16* vb = kb + 8388608;        // transposed [bh][64][2048], k-permuted
  u16* ao = vb + 8388608;        // 8192*1024

  // allow 128 KB dynamic LDS for the 4-phase QKV GEMM (idempotent, capture-safe)
  hipFuncSetAttribute((const void*)gemm256,
                      hipFuncAttributeMaxDynamicSharedMemorySize, 131072);

  cvt_x<<<4096, 256, 0, stream>>>(x, xb, 8388608);
  transpose_cvt<<<dim3(96, 32), dim3(32, 8), 0, stream>>>(Wqkv, wqT, 1024, 3072);
  transpose_cvt<<<dim3(32, 32), dim3(32, 8), 0, stream>>>(Wout, woT, 1024, 1024);
  gemm256<<<384, 512, 131072, stream>>>(xb, wqT, bqkv, qb, kb, vb, 3072, 1024, 12);
  attn_kernel<<<dim3(16, 64), 256, 0, stream>>>(qb, kb, vb, ao);
  gemm_proj<8><<<dim3(8, 64), 256, 0, stream>>>(ao, woT, bout, out, 1024, 1024);
}

// Round 14
// 193.252 us; speedup vs baseline: 1.1289x; 1.1289x over previous
//
#include <hip/hip_runtime.h>

typedef unsigned short u16;
typedef unsigned int u32;
typedef u16 u16x4 __attribute__((ext_vector_type(4)));
typedef u16 u16x8 __attribute__((ext_vector_type(8)));
typedef u32 u32x2 __attribute__((ext_vector_type(2)));
typedef u32 u32x4 __attribute__((ext_vector_type(4)));
typedef __bf16 bf16x2 __attribute__((ext_vector_type(2)));
typedef __bf16 bf16x8 __attribute__((ext_vector_type(8)));
typedef float f32x4 __attribute__((ext_vector_type(4)));

__device__ __forceinline__ u16 f2bf(float f) {
  return __builtin_bit_cast(u16, (__bf16)f);
}

__device__ __forceinline__ u32 packbf2(float lo, float hi) {
  bf16x2 t;
  t[0] = (__bf16)lo;
  t[1] = (__bf16)hi;
  return __builtin_bit_cast(u32, t);
}

__device__ __forceinline__ f32x4 mfma16(bf16x8 a, bf16x8 b, f32x4 c) {
  return __builtin_amdgcn_mfma_f32_16x16x32_bf16(a, b, c, 0, 0, 0);
}

#define GLOAD_LDS16(gsrc, ldst)                                              \
  __builtin_amdgcn_global_load_lds(                                          \
      (const __attribute__((address_space(1))) void*)(gsrc),                 \
      (__attribute__((address_space(3))) void*)(ldst), 16, 0, 0)

// ------------- transpose + convert: in [R][C] f32 -> out [C][R] bf16 -------------
__global__ __launch_bounds__(256) void transpose_cvt(const float* __restrict__ in,
                                                     u16* __restrict__ out,
                                                     int R, int C) {
  __shared__ float tile[32][33];
  int gx = blockIdx.x * 32, gy = blockIdx.y * 32;
  int tx = threadIdx.x, ty = threadIdx.y;
#pragma unroll
  for (int i = 0; i < 4; i++)
    tile[ty + i * 8][tx] = in[(size_t)(gy + ty + i * 8) * C + gx + tx];
  __syncthreads();
#pragma unroll
  for (int i = 0; i < 4; i++) {
    int c = ty + i * 8;
    out[(size_t)(gx + c) * R + gy + tx] = f2bf(tile[tx][c]);
  }
}

// ------------- QKV GEMM with FUSED fp32->bf16 A-conversion ----------------------
// C[8192,3072] = X[8192,1024](fp32) * WqkvT[3072,1024]^T. R7/R12 structure:
// 128^2 tile, BK=32, 3 rotating LDS bufs (48 KB, 3 blk/CU), counted vmcnt.
// A path: fp32 global -> regs (coalesced, unswizzled) -> cvt_pk -> swizzled
// ds_write_b128 (write-side swizzle = read-side swizzle, rule 21).
// B path: pre-swizzled global_load_lds (unchanged). Per step t:
//   issue A-loads(t+2)->rs[t%2], B-gload(t+2)->buf[(t+2)%3];
//   cvt rs[(t+1)%2] -> ds_write buf[(t+1)%3]   (regs 1 full step old);
//   ds_read buf[t%3] + 16 MFMA;
//   lgkm(0) + vmcnt(6) + barrier  (vmcnt(0) on last staged step).
// Epilogue: scatter q (x 0.125*log2e), k, v^T (k-permuted, vectorized).
__global__ __launch_bounds__(256, 3) void gemm_qkv(
    const float* __restrict__ X, const u16* __restrict__ Bt,
    const float* __restrict__ bias, u16* __restrict__ qb, u16* __restrict__ kb,
    u16* __restrict__ vb) {
  const int K = 1024, NT = 32;
  __shared__ u16 As[3][128 * 32];
  __shared__ u16 Bs[3][128 * 32];
  const int tid = threadIdx.x;
  const int wave = tid >> 6;
  const int lane = tid & 63;
  const int wr = wave >> 1, wc = wave & 1;
  const int l15 = lane & 15, l4 = lane >> 4;

  // XCD grouping: 8 consecutive row-panels per XCD
  const int id = blockIdx.y * 24 + blockIdx.x;
  const int xcd = id & 7;
  const int j = id >> 3;
  const int bm = (xcd * 8 + j / 24) * 128;
  const int bn = (j % 24) * 128;

  const int srow = wave * 16 + (lane >> 2);  // + c*64
  const int slch = lane & 3;
  const int ldst = wave * 512;

  const float* Xbase = X + (size_t)bm * K;
  const u16* Bbase = Bt + (size_t)bn * K;

  f32x4 acc[4][4] = {};
  f32x4 rs0[2][2], rs1[2][2];  // two A reg-sets: [c][half], 8 floats each c

  auto STAGE_B = [&](int buf, int k0) {
#pragma unroll
    for (int c = 0; c < 2; c++) {
      const int row = c * 64 + srow;
      const int sch = slch ^ ((row >> 1) & 3);
      GLOAD_LDS16(Bbase + (size_t)row * K + k0 + sch * 8,
                  &Bs[buf][c * 2048 + ldst]);
    }
  };
  auto LOAD_A = [&](f32x4 (&rs)[2][2], int k0) {
#pragma unroll
    for (int c = 0; c < 2; c++) {
      const float* p = Xbase + (size_t)(c * 64 + srow) * K + k0 + slch * 8;
      rs[c][0] = *(const f32x4*)(p);
      rs[c][1] = *(const f32x4*)(p + 4);
    }
  };
  auto CVT_WRITE_A = [&](f32x4 (&rs)[2][2], int buf) {
#pragma unroll
    for (int c = 0; c < 2; c++) {
      const int row = c * 64 + srow;
      const int sch = slch ^ ((row >> 1) & 3);
      u32x4 w;
      w[0] = packbf2(rs[c][0][0], rs[c][0][1]);
      w[1] = packbf2(rs[c][0][2], rs[c][0][3]);
      w[2] = packbf2(rs[c][1][0], rs[c][1][1]);
      w[3] = packbf2(rs[c][1][2], rs[c][1][3]);
      *(u32x4*)&As[buf][row * 32 + sch * 8] = w;
    }
  };

  // prologue: tiles 0,1 in flight; A(0) converted+written now
  LOAD_A(rs0, 0);
  STAGE_B(0, 0);
  LOAD_A(rs1, 32);
  STAGE_B(1, 32);
  CVT_WRITE_A(rs0, 0);  // compiler waits rs0's loads
  asm volatile("s_waitcnt lgkmcnt(0)\n\ts_waitcnt vmcnt(6)" ::: "memory");
  __builtin_amdgcn_sched_barrier(0);
  asm volatile("s_barrier" ::: "memory");

#define QSTEP(CUR, NXT, STG, RSL, RSC, T)                                     \
  {                                                                           \
    if ((T) + 2 < NT) {                                                       \
      LOAD_A(RSL, ((T) + 2) * 32);                                            \
      STAGE_B(STG, ((T) + 2) * 32);                                           \
    }                                                                         \
    if ((T) + 1 < NT) CVT_WRITE_A(RSC, NXT);                                  \
    bf16x8 af[4], bfr[4];                                                     \
    _Pragma("unroll") for (int mi = 0; mi < 4; mi++) {                        \
      const int row = wr * 64 + mi * 16 + l15;                                \
      af[mi] =                                                                \
          *(const bf16x8*)&As[CUR][row * 32 + ((l4 ^ ((row >> 1) & 3)) * 8)]; \
    }                                                                         \
    _Pragma("unroll") for (int ni = 0; ni < 4; ni++) {                        \
      const int row = wc * 64 + ni * 16 + l15;                                \
      bfr[ni] =                                                               \
          *(const bf16x8*)&Bs[CUR][row * 32 + ((l4 ^ ((row >> 1) & 3)) * 8)]; \
    }                                                                         \
    __builtin_amdgcn_s_setprio(1);                                            \
    _Pragma("unroll") for (int mi = 0; mi < 4; mi++)                          \
        _Pragma("unroll") for (int ni = 0; ni < 4; ni++) acc[mi][ni] =        \
            mfma16(af[mi], bfr[ni], acc[mi][ni]);                             \
    __builtin_amdgcn_s_setprio(0);                                            \
    if ((T) + 1 < NT) {                                                       \
      if ((T) + 2 < NT)                                                       \
        asm volatile("s_waitcnt lgkmcnt(0)\n\ts_waitcnt vmcnt(6)" :::         \
                         "memory");                                           \
      else                                                                    \
        asm volatile("s_waitcnt lgkmcnt(0)\n\ts_waitcnt vmcnt(0)" :::         \
                         "memory");                                           \
      __builtin_amdgcn_sched_barrier(0);                                      \
      asm volatile("s_barrier" ::: "memory");                                 \
    }                                                                         \
  }

  for (int tt = 0; tt < 30; tt += 6) {
    QSTEP(0, 1, 2, rs0, rs1, tt + 0);
    QSTEP(1, 2, 0, rs1, rs0, tt + 1);
    QSTEP(2, 0, 1, rs0, rs1, tt + 2);
    QSTEP(0, 1, 2, rs1, rs0, tt + 3);
    QSTEP(1, 2, 0, rs0, rs1, tt + 4);
    QSTEP(2, 0, 1, rs1, rs0, tt + 5);
  }
  QSTEP(0, 1, 2, rs0, rs1, 30);
  QSTEP(1, 2, 0, rs1, rs0, 31);
#undef QSTEP

  // ---- QKV scatter epilogue ----
#pragma unroll
  for (int mi = 0; mi < 4; mi++) {
#pragma unroll
    for (int ni = 0; ni < 4; ni++) {
      const int col = bn + wc * 64 + ni * 16 + l15;
      const float bv = bias[col];
      const int row0 = bm + wr * 64 + mi * 16 + l4 * 4;
      const int which = col >> 10;
      const int hc = col & 1023;
      const int h = hc >> 6, d = hc & 63;
      if (which == 2) {
        // v^T, k-permuted: o=16n+4a+r -> o'=32*(n>>1)+8a+4*(n&1)+r; r stays in
        // low bits -> 4 consecutive tp -> one u16x4 store.
        const int row = row0;
        const int b = row >> 11, tt2 = row & 2047;
        const int o = tt2 & 63;
        const int op = (o & 3) | (((o >> 4) & 1) << 2) | (((o >> 2) & 3) << 3) |
                       ((o >> 5) << 5);
        const int tp = (tt2 & ~63) | op;
        u16x4 vv;
#pragma unroll
        for (int r = 0; r < 4; r++) vv[r] = f2bf(acc[mi][ni][r] + bv);
        *(u16x4*)&vb[((size_t)(b * 16 + h) * 64 + d) * 2048 + tp] = vv;
      } else {
#pragma unroll
        for (int r = 0; r < 4; r++) {
          const int row = row0 + r;
          const int b = row >> 11, tt2 = row & 2047;
          const float v = acc[mi][ni][r] + bv;
          if (which == 0)
            // 0.125 (1/sqrt(64)) * log2(e): softmax done in exp2 domain
            qb[((size_t)(b * 16 + h) * 2048 + tt2) * 64 + d] =
                f2bf(v * 0.18033688f);
          else
            kb[((size_t)(b * 16 + h) * 2048 + tt2) * 64 + d] = f2bf(v);
        }
      }
    }
  }
}

// ---------------- 128x128 GEMM (out-proj, R7 structure): fp32 out + bias --------
template <int GX>
__global__ __launch_bounds__(256, 3) void gemm_proj(
    const u16* __restrict__ A, const u16* __restrict__ Bt,
    const float* __restrict__ bias, float* __restrict__ fout, int N, int K) {
  __shared__ u16 As[3][128 * 32];
  __shared__ u16 Bs[3][128 * 32];
  const int tid = threadIdx.x;
  const int wave = tid >> 6;
  const int lane = tid & 63;
  const int wr = wave >> 1, wc = wave & 1;
  const int l15 = lane & 15, l4 = lane >> 4;

  const int id = blockIdx.y * GX + blockIdx.x;
  const int xcd = id & 7;
  const int j = id >> 3;
  const int bm = (xcd * 8 + j / GX) * 128;
  const int bn = (j % GX) * 128;

  const int srow = wave * 16 + (lane >> 2);
  const int slch = lane & 3;
  const int ldst = wave * 512;

  const u16* Abase = A + (size_t)bm * K;
  const u16* Bbase = Bt + (size_t)bn * K;

  f32x4 acc[4][4] = {};

  auto STAGE = [&](int buf, int k0) {
#pragma unroll
    for (int c = 0; c < 2; c++) {
      const int row = c * 64 + srow;
      const int sch = slch ^ ((row >> 1) & 3);
      GLOAD_LDS16(Abase + (size_t)row * K + k0 + sch * 8,
                  &As[buf][c * 2048 + ldst]);
      GLOAD_LDS16(Bbase + (size_t)row * K + k0 + sch * 8,
                  &Bs[buf][c * 2048 + ldst]);
    }
  };

  const int NT = K >> 5;
  STAGE(0, 0);
  STAGE(1, 32);
  int cur = 0;
  for (int t = 0; t < NT; ++t) {
    if (t + 1 < NT) {
      asm volatile("s_waitcnt lgkmcnt(0)\n\ts_waitcnt vmcnt(4)" ::: "memory");
    } else {
      asm volatile("s_waitcnt lgkmcnt(0)\n\ts_waitcnt vmcnt(0)" ::: "memory");
    }
    __builtin_amdgcn_sched_barrier(0);
    asm volatile("s_barrier" ::: "memory");

    if (t + 2 < NT) {
      int stg = cur + 2;
      if (stg >= 3) stg -= 3;
      STAGE(stg, (t + 2) * 32);
    }

    const u16* as = As[cur];
    const u16* bs = Bs[cur];
    bf16x8 af[4], bfr[4];
#pragma unroll
    for (int mi = 0; mi < 4; mi++) {
      const int row = wr * 64 + mi * 16 + l15;
      af[mi] = *(const bf16x8*)&as[row * 32 + ((l4 ^ ((row >> 1) & 3)) * 8)];
    }
#pragma unroll
    for (int ni = 0; ni < 4; ni++) {
      const int row = wc * 64 + ni * 16 + l15;
      bfr[ni] = *(const bf16x8*)&bs[row * 32 + ((l4 ^ ((row >> 1) & 3)) * 8)];
    }
    __builtin_amdgcn_s_setprio(1);
#pragma unroll
    for (int mi = 0; mi < 4; mi++)
#pragma unroll
      for (int ni = 0; ni < 4; ni++)
        acc[mi][ni] = mfma16(af[mi], bfr[ni], acc[mi][ni]);
    __builtin_amdgcn_s_setprio(0);
    cur = (cur == 2) ? 0 : cur + 1;
  }

#pragma unroll
  for (int mi = 0; mi < 4; mi++) {
#pragma unroll
    for (int ni = 0; ni < 4; ni++) {
      const int col = bn + wc * 64 + ni * 16 + l15;
      const float bv = bias[col];
      const int row0 = bm + wr * 64 + mi * 16 + l4 * 4;
#pragma unroll
      for (int r = 0; r < 4; r++)
        fout[(size_t)(row0 + r) * N + col] = acc[mi][ni][r] + bv;
    }
  }
}

// ---------------- flash attention (swapped-operand, transposed O) ----------------
// Q,K: [64 bh][2048][64] bf16 (Q pre-scaled by 0.125*log2e)
// Vt: [64 bh][64][2048] bf16, k-axis PERMUTED within 64-blocks (see epilogue)
// O: [4 b][2048 t][1024] bf16. STATIC-MAX softmax (p = exp2(s-16), 1/l cancels).
__global__ __launch_bounds__(256, 4) void attn_kernel(const u16* __restrict__ Q,
                                                      const u16* __restrict__ Kg,
                                                      const u16* __restrict__ Vt,
                                                      u16* __restrict__ O) {
  __shared__ u16 Ks[2][64 * 64];
  __shared__ u16 Vs[2][64 * 64];
  const int tid = threadIdx.x;
  const int wave = tid >> 6;
  const int lane = tid & 63;
  const int l15 = lane & 15, l4 = lane >> 4;

  const int id = blockIdx.y * 16 + blockIdx.x;
  const int xcd = id & 7;
  const int j = id >> 3;
  const int bh = xcd * 8 + (j >> 4);
  const int qt = j & 15;

  const u16* qg = Q + ((size_t)bh * 2048 + qt * 128 + wave * 32) * 64;
  bf16x8 qf[2][2];
#pragma unroll
  for (int mi = 0; mi < 2; mi++)
#pragma unroll
    for (int kg2 = 0; kg2 < 2; kg2++)
      qf[mi][kg2] = *(const bf16x8*)&qg[(mi * 16 + l15) * 64 + kg2 * 32 + l4 * 8];

  float lsum[2] = {0.f, 0.f};
  f32x4 oacc[4][2] = {};

  const int srow = wave * 8 + (lane >> 3);
  const int slch = lane & 7;
  const int ldst = wave * 512;
  const u16* kbase = Kg + (size_t)bh * 2048 * 64;
  const u16* vbase = Vt + (size_t)bh * 64 * 2048;

  auto STAGE = [&](int buf, int kt) {
#pragma unroll
    for (int c = 0; c < 2; c++) {
      const int row = c * 32 + srow;
      const int sch = slch ^ (row & 7);
      GLOAD_LDS16(kbase + (size_t)(kt * 64 + row) * 64 + sch * 8,
                  &Ks[buf][c * 2048 + ldst]);
      GLOAD_LDS16(vbase + (size_t)row * 2048 + kt * 64 + sch * 8,
                  &Vs[buf][c * 2048 + ldst]);
    }
  };

  STAGE(0, 0);
  int cur = 0;
  for (int kt = 0; kt < 32; kt++) {
    __syncthreads();
    if (kt + 1 < 32) STAGE(cur ^ 1, kt + 1);
    const u16* ks = Ks[cur];
    const u16* vs = Vs[cur];

    f32x4 sacc[2][4] = {};
    __builtin_amdgcn_s_setprio(1);
#pragma unroll
    for (int kg2 = 0; kg2 < 2; kg2++) {
#pragma unroll
      for (int ni = 0; ni < 4; ni++) {
        const int row = ni * 16 + l15;
        bf16x8 kf =
            *(const bf16x8*)&ks[row * 64 + (((kg2 * 4 + l4) ^ (row & 7)) * 8)];
#pragma unroll
        for (int mi = 0; mi < 2; mi++)
          sacc[mi][ni] = mfma16(kf, qf[mi][kg2], sacc[mi][ni]);
      }
    }
    __builtin_amdgcn_s_setprio(0);

#pragma unroll
    for (int mi = 0; mi < 2; mi++) {
      float rs = 0.f;
#pragma unroll
      for (int ni = 0; ni < 4; ni++)
#pragma unroll
        for (int r = 0; r < 4; r++) {
          const float p = __builtin_amdgcn_exp2f(sacc[mi][ni][r] - 16.0f);
          sacc[mi][ni][r] = p;
          rs += p;
        }
      lsum[mi] += rs;
    }

#pragma unroll
    for (int kg2 = 0; kg2 < 2; kg2++) {
      bf16x8 pf[2];
#pragma unroll
      for (int mi = 0; mi < 2; mi++) {
        u32x4 praw;
        praw[0] = packbf2(sacc[mi][2 * kg2][0], sacc[mi][2 * kg2][1]);
        praw[1] = packbf2(sacc[mi][2 * kg2][2], sacc[mi][2 * kg2][3]);
        praw[2] = packbf2(sacc[mi][2 * kg2 + 1][0], sacc[mi][2 * kg2 + 1][1]);
        praw[3] = packbf2(sacc[mi][2 * kg2 + 1][2], sacc[mi][2 * kg2 + 1][3]);
        pf[mi] = __builtin_bit_cast(bf16x8, praw);
      }
      __builtin_amdgcn_s_setprio(1);
#pragma unroll
      for (int di = 0; di < 4; di++) {
        const int row = di * 16 + l15;
        bf16x8 vf =
            *(const bf16x8*)&vs[row * 64 + (((kg2 * 4 + l4) ^ (row & 7)) * 8)];
#pragma unroll
        for (int mi = 0; mi < 2; mi++)
          oacc[di][mi] = mfma16(vf, pf[mi], oacc[di][mi]);
      }
      __builtin_amdgcn_s_setprio(0);
    }
    cur ^= 1;
  }

  const int b = bh >> 4, h = bh & 15;
#pragma unroll
  for (int mi = 0; mi < 2; mi++) {
    float lr = lsum[mi];
    lr += __shfl_xor(lr, 16);
    lr += __shfl_xor(lr, 32);
    const float invl = 1.0f / lr;
    const int t = qt * 128 + wave * 32 + mi * 16 + l15;
#pragma unroll
    for (int di = 0; di < 4; di++) {
      u16x4 o;
#pragma unroll
      for (int r = 0; r < 4; r++) o[r] = f2bf(oacc[di][mi][r] * invl);
      *(u16x4*)&O[((size_t)b * 2048 + t) * 1024 + h * 64 + di * 16 + l4 * 4] = o;
    }
  }
}

extern "C" void kernel_launch(void* const* d_in, const int* in_sizes, int n_in,
                              void* d_out, int out_size, void* d_ws, size_t ws_size,
                              hipStream_t stream) {
  const float* x = (const float*)d_in[0];
  const float* Wqkv = (const float*)d_in[1];
  const float* bqkv = (const float*)d_in[2];
  const float* Wout = (const float*)d_in[3];
  const float* bout = (const float*)d_in[4];
  float* out = (float*)d_out;

  u16* ws = (u16*)d_ws;
  u16* wqT = ws;                 // 3072*1024
  u16* woT = wqT + 3145728;      // 1024*1024
  u16* qb = woT + 1048576;       // 64*2048*64
  u16* kb = qb + 8388608;
  u16* vb = kb + 8388608;        // transposed [bh][64][2048], k-permuted
  u16* ao = vb + 8388608;        // 8192*1024

  transpose_cvt<<<dim3(96, 32), dim3(32, 8), 0, stream>>>(Wqkv, wqT, 1024, 3072);
  transpose_cvt<<<dim3(32, 32), dim3(32, 8), 0, stream>>>(Wout, woT, 1024, 1024);
  gemm_qkv<<<dim3(24, 64), 256, 0, stream>>>(x, wqT, bqkv, qb, kb, vb);
  attn_kernel<<<dim3(16, 64), 256, 0, stream>>>(qb, kb, vb, ao);
  gemm_proj<8><<<dim3(8, 64), 256, 0, stream>>>(ao, woT, bout, out, 1024, 1024);
}